// Round 2
// baseline (226.893 us; speedup 1.0000x reference)
//
#include <hip/hip_runtime.h>

// DiscriminativeLoss: data [32, 512, 1024] f32 (D-planar), labels [512,1024] i32 in [0,16)
// out: scalar f32 loss.
//
// ws float layout (16-float / 64 B stride padding so each atomic target owns a cache line):
//   sums_p[(k*32 + d) * 16]  : [0, 8192)
//   counts_p[k * 16]         : [8192, 8448)
//   ct2[d*32 + k] (dup +16)  : [8448, 9472)   centers, transposed + duplicated for bank spread

constexpr int KC = 16;
constexpr int DD = 32;
constexpr int NN = 512 * 1024;
constexpr int N4 = NN / 4;                        // 131072 float4 groups per d-plane
constexpr int CHUNKS = 16;
constexpr int GROUPS_PER_CHUNK = N4 / CHUNKS;     // 8192
constexpr int K1_ITERS = GROUPS_PER_CHUNK / 256;  // 32

constexpr int WS_SUMS = 0;
constexpr int WS_CNTS = 8192;
constexpr int WS_CT2  = 8448;
constexpr int WS_ZERO_FLOATS = 8448;

__global__ __launch_bounds__(256) void k1_sums(const float4* __restrict__ data4,
                                               const int4* __restrict__ lab4,
                                               float* __restrict__ ws) {
    const int tid = threadIdx.x;
    const int d = blockIdx.y;
    const bool doCnt = (d == 0);

    // Per-thread private accumulator rows (stride 17 spreads banks; rows private -> no races).
    __shared__ float acc[256 * 17];
    __shared__ float cnt[256 * 17];
    float* arow = acc + tid * 17;
    float* crow = cnt + tid * 17;
#pragma unroll
    for (int k = 0; k < KC; ++k) arow[k] = 0.f;
    if (doCnt) {
#pragma unroll
        for (int k = 0; k < KC; ++k) crow[k] = 0.f;
    }

    const int base = blockIdx.x * GROUPS_PER_CHUNK + tid;
    const float4* dplane = data4 + (size_t)d * N4;

    for (int it = 0; it < K1_ITERS; ++it) {
        const int g = base + it * 256;
        const float4 v = dplane[g];
        const int4 lb = lab4[g];
        // ds_add_f32 (no return): 1 LDS op per element instead of read+add+write.
        atomicAdd(&arow[lb.x], v.x);
        atomicAdd(&arow[lb.y], v.y);
        atomicAdd(&arow[lb.z], v.z);
        atomicAdd(&arow[lb.w], v.w);
        if (doCnt) {
            atomicAdd(&crow[lb.x], 1.f);
            atomicAdd(&crow[lb.y], 1.f);
            atomicAdd(&crow[lb.z], 1.f);
            atomicAdd(&crow[lb.w], 1.f);
        }
    }
    __syncthreads();

    // Transposed epilogue: thread t handles cluster k = t>>4, row-segment seg = t&15.
    const int k = tid >> 4, seg = tid & 15;
    float s = 0.f;
#pragma unroll
    for (int i = 0; i < 16; ++i) s += acc[(seg * 16 + i) * 17 + k];
#pragma unroll
    for (int off = 8; off > 0; off >>= 1) s += __shfl_down(s, off, 16);
    if (seg == 0) atomicAdd(&ws[WS_SUMS + (k * DD + d) * 16], s);
    if (doCnt) {
        float c = 0.f;
#pragma unroll
        for (int i = 0; i < 16; ++i) c += cnt[(seg * 16 + i) * 17 + k];
#pragma unroll
        for (int off = 8; off > 0; off >>= 1) c += __shfl_down(c, off, 16);
        if (seg == 0) atomicAdd(&ws[WS_CNTS + k * 16], c);
    }
}

__global__ __launch_bounds__(256) void k2_centers(float* __restrict__ ws,
                                                  float* __restrict__ out) {
    __shared__ float cent[KC][DD + 1];
    __shared__ float red[256];
    const int tid = threadIdx.x;

    for (int idx = tid; idx < KC * DD; idx += 256) {
        const int k = idx / DD, d = idx % DD;
        const float c = ws[WS_SUMS + idx * 16] / ws[WS_CNTS + k * 16];
        cent[k][d] = c;
        ws[WS_CT2 + d * 32 + k] = c;        // centers_t, duplicated for bank spread
        ws[WS_CT2 + d * 32 + 16 + k] = c;
    }
    __syncthreads();

    // 256 threads = 256 ordered pairs (i, j).
    const int i = tid >> 4, j = tid & 15;
    float sq = 0.f;
#pragma unroll
    for (int d = 0; d < DD; ++d) {
        const float df = cent[i][d] - cent[j][d];
        sq += df * df;
    }
    float val = 0.f;
    if (i != j) {
        const float pd = sqrtf(sq);
        const float t = fmaxf(3.0f - pd, 0.f);    // 2*DELTA_DIST = 3.0
        val = t * t * (1.0f / (KC * (KC - 1)));
    } else {
        float s2 = 0.f;
#pragma unroll
        for (int d = 0; d < DD; ++d) s2 += cent[i][d] * cent[i][d];
        val = sqrtf(s2) * (0.001f / KC);           // reg_term
    }
    red[tid] = val;
    __syncthreads();
    for (int off = 128; off > 0; off >>= 1) {
        if (tid < off) red[tid] += red[tid + off];
        __syncthreads();
    }
    if (tid == 0) out[0] = red[0];                 // plain store; k3 atomicAdds on top
}

__global__ __launch_bounds__(256) void k3_var(const float4* __restrict__ data4,
                                              const int4* __restrict__ lab4,
                                              const float* __restrict__ ws,
                                              float* __restrict__ out) {
    __shared__ float ct2[DD * 32];
    const int tid = threadIdx.x;
    for (int idx = tid; idx < DD * 32; idx += 256) ct2[idx] = ws[WS_CT2 + idx];
    __syncthreads();

    const int g = blockIdx.x * 256 + tid;          // one float4 group of points
    const int4 lb = lab4[g];
    const int dup = (tid & 32) >> 1;               // lanes 32-63 read the +16 duplicate
    const int o0 = lb.x + dup, o1 = lb.y + dup, o2 = lb.z + dup, o3 = lb.w + dup;

    float s0 = 0.f, s1 = 0.f, s2 = 0.f, s3 = 0.f;
#pragma unroll 8
    for (int d = 0; d < DD; ++d) {
        const float4 v = data4[(size_t)d * N4 + g];
        const float* ctd = ct2 + d * 32;
        const float d0 = ctd[o0] - v.x; s0 += d0 * d0;
        const float d1 = ctd[o1] - v.y; s1 += d1 * d1;
        const float d2 = ctd[o2] - v.z; s2 += d2 * d2;
        const float d3 = ctd[o3] - v.w; s3 += d3 * d3;
    }
    const float h0 = fmaxf(sqrtf(s0) - 0.5f, 0.f);
    const float h1 = fmaxf(sqrtf(s1) - 0.5f, 0.f);
    const float h2 = fmaxf(sqrtf(s2) - 0.5f, 0.f);
    const float h3 = fmaxf(sqrtf(s3) - 0.5f, 0.f);
    float lsum = h0 * h0 + h1 * h1 + h2 * h2 + h3 * h3;

#pragma unroll
    for (int off = 32; off > 0; off >>= 1) lsum += __shfl_down(lsum, off);
    __shared__ float wred[4];
    if ((tid & 63) == 0) wred[tid >> 6] = lsum;
    __syncthreads();
    if (tid == 0) {
        const float s = wred[0] + wred[1] + wred[2] + wred[3];
        atomicAdd(out, s * (1.0f / KC));
    }
}

extern "C" void kernel_launch(void* const* d_in, const int* in_sizes, int n_in,
                              void* d_out, int out_size, void* d_ws, size_t ws_size,
                              hipStream_t stream) {
    const float4* data4 = (const float4*)d_in[0];
    const int4* lab4 = (const int4*)d_in[1];
    float* out = (float*)d_out;
    float* ws = (float*)d_ws;

    hipMemsetAsync(ws, 0, WS_ZERO_FLOATS * sizeof(float), stream);

    k1_sums<<<dim3(CHUNKS, DD), 256, 0, stream>>>(data4, lab4, ws);
    k2_centers<<<1, 256, 0, stream>>>(ws, out);
    k3_var<<<512, 256, 0, stream>>>(data4, lab4, ws, out);
}

// Round 3
// 122.047 us; speedup vs baseline: 1.8591x; 1.8591x over previous
//
#include <hip/hip_runtime.h>

// DiscriminativeLoss: data [32, 512, 1024] f32 (D-planar), labels [512,1024] i32 in [0,16)
// out: scalar f32 loss.
//
// NOTE (round-2 lesson): LDS float atomicAdd (ds_add_f32) costs ~300 cyc/wave-instr on
// gfx950 (serialized per lane). Plain read+add+write RMW on per-thread-private rows is
// ~25x faster. Never use LDS float atomics in the hot loop.
//
// ws float layout (16-float / 64 B stride so each global atomic target owns a cache line):
//   sums_p[(k*32 + d) * 16]  : [0, 8192)
//   counts_p[k * 16]         : [8192, 8448)
//   ct2[d*32 + k] (dup +16)  : [8448, 9472)   centers, transposed + duplicated for bank spread

constexpr int KC = 16;
constexpr int DD = 32;
constexpr int NN = 512 * 1024;
constexpr int N4 = NN / 4;                        // 131072 float4 groups per d-plane
constexpr int CHUNKS = 32;
constexpr int GROUPS_PER_CHUNK = N4 / CHUNKS;     // 4096
constexpr int K1_ITERS = GROUPS_PER_CHUNK / 256;  // 16

constexpr int WS_SUMS = 0;
constexpr int WS_CNTS = 8192;
constexpr int WS_CT2  = 8448;
constexpr int WS_ZERO_FLOATS = 8448;

__global__ __launch_bounds__(256) void k1_sums(const float4* __restrict__ data4,
                                               const int4* __restrict__ lab4,
                                               float* __restrict__ ws) {
    const int tid = threadIdx.x;
    const int d = blockIdx.y;
    const bool doCnt = (d == 0);

    // Per-thread private accumulator rows (stride 17 spreads banks; rows private -> no
    // races, no atomics). 2x 17.4 KB -> 4 blocks/CU.
    __shared__ float acc[256 * 17];
    __shared__ float cnt[256 * 17];
    float* arow = acc + tid * 17;
    float* crow = cnt + tid * 17;
#pragma unroll
    for (int k = 0; k < KC; ++k) arow[k] = 0.f;
    if (doCnt) {
#pragma unroll
        for (int k = 0; k < KC; ++k) crow[k] = 0.f;
    }

    const int base = blockIdx.x * GROUPS_PER_CHUNK + tid;
    const float4* dplane = data4 + (size_t)d * N4;

    for (int it = 0; it < K1_ITERS; ++it) {
        const int g = base + it * 256;
        const float4 v = dplane[g];
        const int4 lb = lab4[g];
        // plain RMW: ds_read_b32 + v_add_f32 + ds_write_b32 (rows are thread-private)
        arow[lb.x] += v.x;
        arow[lb.y] += v.y;
        arow[lb.z] += v.z;
        arow[lb.w] += v.w;
        if (doCnt) {
            crow[lb.x] += 1.f;
            crow[lb.y] += 1.f;
            crow[lb.z] += 1.f;
            crow[lb.w] += 1.f;
        }
    }
    __syncthreads();

    // Transposed epilogue: thread t handles cluster k = t>>4, row-segment seg = t&15.
    const int k = tid >> 4, seg = tid & 15;
    float s = 0.f;
#pragma unroll
    for (int i = 0; i < 16; ++i) s += acc[(seg * 16 + i) * 17 + k];
#pragma unroll
    for (int off = 8; off > 0; off >>= 1) s += __shfl_down(s, off, 16);
    if (seg == 0) atomicAdd(&ws[WS_SUMS + (k * DD + d) * 16], s);
    if (doCnt) {
        float c = 0.f;
#pragma unroll
        for (int i = 0; i < 16; ++i) c += cnt[(seg * 16 + i) * 17 + k];
#pragma unroll
        for (int off = 8; off > 0; off >>= 1) c += __shfl_down(c, off, 16);
        if (seg == 0) atomicAdd(&ws[WS_CNTS + k * 16], c);
    }
}

__global__ __launch_bounds__(256) void k2_centers(float* __restrict__ ws,
                                                  float* __restrict__ out) {
    __shared__ float cent[KC][DD + 1];
    __shared__ float red[256];
    const int tid = threadIdx.x;

    for (int idx = tid; idx < KC * DD; idx += 256) {
        const int k = idx / DD, d = idx % DD;
        const float c = ws[WS_SUMS + idx * 16] / ws[WS_CNTS + k * 16];
        cent[k][d] = c;
        ws[WS_CT2 + d * 32 + k] = c;        // centers_t, duplicated for bank spread
        ws[WS_CT2 + d * 32 + 16 + k] = c;
    }
    __syncthreads();

    // 256 threads = 256 ordered pairs (i, j).
    const int i = tid >> 4, j = tid & 15;
    float sq = 0.f;
#pragma unroll
    for (int d = 0; d < DD; ++d) {
        const float df = cent[i][d] - cent[j][d];
        sq += df * df;
    }
    float val = 0.f;
    if (i != j) {
        const float pd = sqrtf(sq);
        const float t = fmaxf(3.0f - pd, 0.f);    // 2*DELTA_DIST = 3.0
        val = t * t * (1.0f / (KC * (KC - 1)));
    } else {
        float s2 = 0.f;
#pragma unroll
        for (int d = 0; d < DD; ++d) s2 += cent[i][d] * cent[i][d];
        val = sqrtf(s2) * (0.001f / KC);           // reg_term
    }
    red[tid] = val;
    __syncthreads();
    for (int off = 128; off > 0; off >>= 1) {
        if (tid < off) red[tid] += red[tid + off];
        __syncthreads();
    }
    if (tid == 0) out[0] = red[0];                 // plain store; k3 atomicAdds on top
}

__global__ __launch_bounds__(256) void k3_var(const float4* __restrict__ data4,
                                              const int4* __restrict__ lab4,
                                              const float* __restrict__ ws,
                                              float* __restrict__ out) {
    __shared__ float ct2[DD * 32];
    const int tid = threadIdx.x;
    for (int idx = tid; idx < DD * 32; idx += 256) ct2[idx] = ws[WS_CT2 + idx];
    __syncthreads();

    const int g = blockIdx.x * 256 + tid;          // one float4 group of points
    const int4 lb = lab4[g];
    const int dup = (tid & 32) >> 1;               // lanes 32-63 read the +16 duplicate
    const int o0 = lb.x + dup, o1 = lb.y + dup, o2 = lb.z + dup, o3 = lb.w + dup;

    float s0 = 0.f, s1 = 0.f, s2 = 0.f, s3 = 0.f;
#pragma unroll 8
    for (int d = 0; d < DD; ++d) {
        const float4 v = data4[(size_t)d * N4 + g];
        const float* ctd = ct2 + d * 32;
        const float d0 = ctd[o0] - v.x; s0 += d0 * d0;
        const float d1 = ctd[o1] - v.y; s1 += d1 * d1;
        const float d2 = ctd[o2] - v.z; s2 += d2 * d2;
        const float d3 = ctd[o3] - v.w; s3 += d3 * d3;
    }
    const float h0 = fmaxf(sqrtf(s0) - 0.5f, 0.f);
    const float h1 = fmaxf(sqrtf(s1) - 0.5f, 0.f);
    const float h2 = fmaxf(sqrtf(s2) - 0.5f, 0.f);
    const float h3 = fmaxf(sqrtf(s3) - 0.5f, 0.f);
    float lsum = h0 * h0 + h1 * h1 + h2 * h2 + h3 * h3;

#pragma unroll
    for (int off = 32; off > 0; off >>= 1) lsum += __shfl_down(lsum, off);
    __shared__ float wred[4];
    if ((tid & 63) == 0) wred[tid >> 6] = lsum;
    __syncthreads();
    if (tid == 0) {
        const float s = wred[0] + wred[1] + wred[2] + wred[3];
        atomicAdd(out, s * (1.0f / KC));
    }
}

extern "C" void kernel_launch(void* const* d_in, const int* in_sizes, int n_in,
                              void* d_out, int out_size, void* d_ws, size_t ws_size,
                              hipStream_t stream) {
    const float4* data4 = (const float4*)d_in[0];
    const int4* lab4 = (const int4*)d_in[1];
    float* out = (float*)d_out;
    float* ws = (float*)d_ws;

    hipMemsetAsync(ws, 0, WS_ZERO_FLOATS * sizeof(float), stream);

    k1_sums<<<dim3(CHUNKS, DD), 256, 0, stream>>>(data4, lab4, ws);
    k2_centers<<<1, 256, 0, stream>>>(ws, out);
    k3_var<<<512, 256, 0, stream>>>(data4, lab4, ws, out);
}

// Round 4
// 119.044 us; speedup vs baseline: 1.9060x; 1.0252x over previous
//
#include <hip/hip_runtime.h>

// DiscriminativeLoss: data [32, 512, 1024] f32 (D-planar), labels [512,1024] i32 in [0,16)
// out: scalar f32 loss.
//
// Lessons so far:
//  - LDS float atomicAdd (ds_add_f32) ~300 cyc/wave-instr on gfx950 -> never in hot loop.
//  - Harness re-poison (268 MB fill ~41us + d_in restore ~21us) is inside the timed
//    window: ~63us fixed. Minimize our dispatches/gaps: 2 kernels, no memset, no atomics
//    in pass 1 (per-chunk partial stores cover every slot -> no zeroing needed).
//
// ws float layout:
//   partials[(k*32 + d)*32 + chunk] : [0, 16384)
//   cpart[k*32 + chunk]             : [16384, 16896)

constexpr int KC = 16;
constexpr int DD = 32;
constexpr int NN = 512 * 1024;
constexpr int N4 = NN / 4;                        // 131072 float4 groups per d-plane
constexpr int CHUNKS = 32;
constexpr int GROUPS_PER_CHUNK = N4 / CHUNKS;     // 4096
constexpr int K1_ITERS = GROUPS_PER_CHUNK / 256;  // 16

constexpr int WS_P  = 0;
constexpr int WS_CP = 16384;

__global__ __launch_bounds__(256) void kA_sums(const float4* __restrict__ data4,
                                               const int4* __restrict__ lab4,
                                               float* __restrict__ ws,
                                               float* __restrict__ out) {
    const int tid = threadIdx.x;
    const int chunk = blockIdx.x;
    const int d = blockIdx.y;
    const bool doCnt = (d == 0);

    if (chunk == 0 && d == 0 && tid == 0) out[0] = 0.f;  // kB atomicAdds on top (next kernel)

    // Per-thread private accumulator rows (stride 17 spreads banks; private -> no atomics).
    __shared__ float acc[256 * 17];
    __shared__ float cnt[256 * 17];
    float* arow = acc + tid * 17;
    float* crow = cnt + tid * 17;
#pragma unroll
    for (int k = 0; k < KC; ++k) arow[k] = 0.f;
    if (doCnt) {
#pragma unroll
        for (int k = 0; k < KC; ++k) crow[k] = 0.f;
    }

    const int base = chunk * GROUPS_PER_CHUNK + tid;
    const float4* dplane = data4 + (size_t)d * N4;

    for (int it = 0; it < K1_ITERS; ++it) {
        const int g = base + it * 256;
        const float4 v = dplane[g];
        const int4 lb = lab4[g];
        arow[lb.x] += v.x;
        arow[lb.y] += v.y;
        arow[lb.z] += v.z;
        arow[lb.w] += v.w;
        if (doCnt) {
            crow[lb.x] += 1.f;
            crow[lb.y] += 1.f;
            crow[lb.z] += 1.f;
            crow[lb.w] += 1.f;
        }
    }
    __syncthreads();

    // Transposed epilogue: thread t -> cluster k = t>>4, row-segment seg = t&15.
    const int k = tid >> 4, seg = tid & 15;
    float s = 0.f;
#pragma unroll
    for (int i = 0; i < 16; ++i) s += acc[(seg * 16 + i) * 17 + k];
#pragma unroll
    for (int off = 8; off > 0; off >>= 1) s += __shfl_down(s, off, 16);
    if (seg == 0) ws[WS_P + (k * DD + d) * CHUNKS + chunk] = s;   // plain store
    if (doCnt) {
        float c = 0.f;
#pragma unroll
        for (int i = 0; i < 16; ++i) c += cnt[(seg * 16 + i) * 17 + k];
#pragma unroll
        for (int off = 8; off > 0; off >>= 1) c += __shfl_down(c, off, 16);
        if (seg == 0) ws[WS_CP + k * CHUNKS + chunk] = c;         // plain store
    }
}

__global__ __launch_bounds__(256) void kB_var(const float4* __restrict__ data4,
                                              const int4* __restrict__ lab4,
                                              const float* __restrict__ ws,
                                              float* __restrict__ out) {
    __shared__ float csum[KC * 33];      // stride 33: bank-spread for (k varies) reads
    __shared__ float ccnt[KC];
    __shared__ float ct2[DD * 32];       // centers_t duplicated (k and k+16 identical)
    const int tid = threadIdx.x;

    // Every block redundantly reduces the 32 chunk-partials (L2-resident, ~66 KB).
    {
        int idx = tid;                   // (k*32 + d), two per thread
        const float* p = ws + WS_P + idx * CHUNKS;
        float s = 0.f;
#pragma unroll
        for (int c = 0; c < CHUNKS; ++c) s += p[c];
        csum[(idx >> 5) * 33 + (idx & 31)] = s;
        idx = tid + 256;
        p = ws + WS_P + idx * CHUNKS;
        s = 0.f;
#pragma unroll
        for (int c = 0; c < CHUNKS; ++c) s += p[c];
        csum[(idx >> 5) * 33 + (idx & 31)] = s;
    }
    if (tid < KC) {
        const float* p = ws + WS_CP + tid * CHUNKS;
        float c = 0.f;
#pragma unroll
        for (int i = 0; i < CHUNKS; ++i) c += p[i];
        ccnt[tid] = c;
    }
    __syncthreads();

    for (int idx = tid; idx < KC * DD; idx += 256) {
        const int k = idx >> 5, d = idx & 31;
        const float c = csum[k * 33 + d] / ccnt[k];
        ct2[d * 32 + k] = c;
        ct2[d * 32 + 16 + k] = c;
    }
    __syncthreads();

    // Block 0 only: pairwise distance term + reg term.
    if (blockIdx.x == 0) {
        const int i = tid >> 4, j = tid & 15;
        float val;
        if (i != j) {
            float sq = 0.f;
#pragma unroll
            for (int d = 0; d < DD; ++d) {
                const float df = ct2[d * 32 + i] - ct2[d * 32 + j];
                sq += df * df;
            }
            const float pd = sqrtf(sq);
            const float t = fmaxf(3.0f - pd, 0.f);            // 2*DELTA_DIST
            val = t * t * (1.0f / (KC * (KC - 1)));
        } else {
            float s2 = 0.f;
#pragma unroll
            for (int d = 0; d < DD; ++d) s2 += ct2[d * 32 + i] * ct2[d * 32 + i];
            val = sqrtf(s2) * (0.001f / KC);                   // reg term
        }
        __shared__ float red[256];
        red[tid] = val;
        __syncthreads();
        for (int off = 128; off > 0; off >>= 1) {
            if (tid < off) red[tid] += red[tid + off];
            __syncthreads();
        }
        if (tid == 0) atomicAdd(out, red[0]);
        __syncthreads();
    }

    // Pass 2: one float4 group per thread (512 blocks x 256 = N4).
    const int g = blockIdx.x * 256 + tid;
    const int4 lb = lab4[g];
    const int dup = (tid & 32) >> 1;     // lanes 32-63 read the +16 duplicate
    const int o0 = lb.x + dup, o1 = lb.y + dup, o2 = lb.z + dup, o3 = lb.w + dup;

    float s0 = 0.f, s1 = 0.f, s2 = 0.f, s3 = 0.f;
#pragma unroll 8
    for (int d = 0; d < DD; ++d) {
        const float4 v = data4[(size_t)d * N4 + g];
        const float* ctd = ct2 + d * 32;
        const float d0 = ctd[o0] - v.x; s0 += d0 * d0;
        const float d1 = ctd[o1] - v.y; s1 += d1 * d1;
        const float d2 = ctd[o2] - v.z; s2 += d2 * d2;
        const float d3 = ctd[o3] - v.w; s3 += d3 * d3;
    }
    const float h0 = fmaxf(sqrtf(s0) - 0.5f, 0.f);
    const float h1 = fmaxf(sqrtf(s1) - 0.5f, 0.f);
    const float h2 = fmaxf(sqrtf(s2) - 0.5f, 0.f);
    const float h3 = fmaxf(sqrtf(s3) - 0.5f, 0.f);
    float lsum = h0 * h0 + h1 * h1 + h2 * h2 + h3 * h3;

#pragma unroll
    for (int off = 32; off > 0; off >>= 1) lsum += __shfl_down(lsum, off);
    __shared__ float wred[4];
    if ((tid & 63) == 0) wred[tid >> 6] = lsum;
    __syncthreads();
    if (tid == 0) {
        const float s = wred[0] + wred[1] + wred[2] + wred[3];
        atomicAdd(out, s * (1.0f / KC));
    }
}

extern "C" void kernel_launch(void* const* d_in, const int* in_sizes, int n_in,
                              void* d_out, int out_size, void* d_ws, size_t ws_size,
                              hipStream_t stream) {
    const float4* data4 = (const float4*)d_in[0];
    const int4* lab4 = (const int4*)d_in[1];
    float* out = (float*)d_out;
    float* ws = (float*)d_ws;

    kA_sums<<<dim3(CHUNKS, DD), 256, 0, stream>>>(data4, lab4, ws, out);
    kB_var<<<512, 256, 0, stream>>>(data4, lab4, ws, out);
}